// Round 6
// baseline (357.334 us; speedup 1.0000x reference)
//
#include <hip/hip_runtime.h>
#include <hip/hip_bf16.h>
#include <math.h>

#define Bq 4
#define Cq 64
#define Hq 160
#define Wq 160
#define HWq (Hq*Wq)      // 25600
#define OUTq 64
#define KKq 576          // Cq*9
#define KS  18           // KKq/32
#define SROW 584         // padded kk row (bf16 units); 1168 B
#define HSTRIDE 72       // halo px stride (ushorts) = 144 B
#define NBLK 1280        // 5 blocks/CU x 256 CUs (capacity by LDS = 6/CU)
#define TPB 5            // fused tiles per block: 6400 / 1280

typedef __attribute__((ext_vector_type(8))) short short8;
typedef __attribute__((ext_vector_type(4))) float float4v;
typedef unsigned short ushort_t;

__device__ __forceinline__ unsigned int f2bfu(float f) {   // RNE, as uint
    unsigned int u = __builtin_bit_cast(unsigned int, f);
    unsigned int r = u + 0x7fffu + ((u >> 16) & 1u);
    return r >> 16;
}
__device__ __forceinline__ float bflo(unsigned int u) {
    return __builtin_bit_cast(float, u << 16);
}
__device__ __forceinline__ float bfhi(unsigned int u) {
    return __builtin_bit_cast(float, u & 0xffff0000u);
}

// ---------------------------------------------------------------------------
// Single persistent kernel:
//  Phase 0a: x NCHW f32 -> xt NHWC bf16 (each block 1-2 tiles of 64hw x 64c)
//  Phase 0b: weight prepack (blocks 0..215): wtf (dcn A-frags, k-major
//            kk=k*64+c), cwf2 (per-tap conv A-frags)
//  Barrier:  device-scope atomic counter (all NBLK blocks co-resident)
//  Phase 1..5: per 16-px tile: halo stage -> offset/mask conv (K-split MFMA)
//            -> tap descriptors -> bilinear sampling -> main MFMA -> store
// LDS: union{transpose tile(16640B) | halo(7776)+partials(4096) | s_s(18688)}
//      + s_pk(6912) = 25,600 B -> 6 blocks/CU capacity, 5 requested.
// ---------------------------------------------------------------------------
__global__ void __launch_bounds__(256, 5) k_all(const float* __restrict__ x,
                                                const float* __restrict__ dcn_w,
                                                const float* __restrict__ off_w,
                                                const float* __restrict__ msk_w,
                                                const float* __restrict__ off_b,
                                                const float* __restrict__ msk_b,
                                                ushort_t* __restrict__ xt,
                                                ushort_t* __restrict__ wtf,
                                                ushort_t* __restrict__ cwf2,
                                                unsigned int* __restrict__ ctr,
                                                float* __restrict__ out) {
    __shared__ __align__(16) char s_mem[16*SROW*2];          // 18,688 B
    __shared__ __align__(16) unsigned int s_pk[144*12];      //  6,912 B
    int bid = blockIdx.x;
    int tid = threadIdx.x, lane = tid & 63, grp = tid >> 6;

    // ---- Phase 0a: transpose x -> xt -------------------------------------
    {
        float (*tile)[65] = (float(*)[65])s_mem;
        for (int t = bid; t < 1600; t += NBLK) {
            int b = t & 3, hw0 = (t >> 2) * 64;
            __syncthreads();
#pragma unroll
            for (int i2 = 0; i2 < 16; ++i2) {
                int c = grp*16 + i2;
                tile[c][lane] = x[(b*Cq + c)*HWq + hw0 + lane];
            }
            __syncthreads();
            int cp = tid & 31, hwg = tid >> 5;
#pragma unroll
            for (int it2 = 0; it2 < 8; ++it2) {
                int hw = it2*8 + hwg;
                unsigned int v = f2bfu(tile[2*cp][hw]) | (f2bfu(tile[2*cp+1][hw]) << 16);
                *(unsigned int*)(xt + ((size_t)b*HWq + hw0 + hw)*64 + 2*cp) = v;
            }
        }
    }
    // ---- Phase 0b: weight prepack ----------------------------------------
    if (bid < 216) {
        int id = bid*256 + tid;
        if (id < 4*KS*512) {
            int j = id & 7, ln = (id>>3) & 63, ks = (id>>9) % KS, g = id/(512*KS);
            int kk = ks*32 + (ln>>4)*8 + j;
            int c  = kk & 63, kt = kk >> 6;
            int m  = g*16 + (ln&15);
            wtf[id] = (ushort_t)f2bfu(dcn_w[m*KKq + c*9 + kt]);
        }
        int id2 = id - 4*KS*512;
        if (id2 >= 0 && id2 < 9*2*2*512) {
            int j = id2 & 7, ln = (id2>>3) & 63;
            int ks2 = (id2>>9) & 1, g = (id2>>10) & 1, k = id2 >> 11;
            int co = g*16 + (ln&15);
            int c  = ks2*32 + (ln>>4)*8 + j;
            float w = 0.f;
            if (co < 18)      w = off_w[co*KKq + c*9 + k];
            else if (co < 27) w = msk_w[(co-18)*KKq + c*9 + k];
            cwf2[id2] = (ushort_t)f2bfu(w);
        }
    }

    // ---- Grid barrier (device-scope; all NBLK blocks co-resident) --------
    __threadfence();
    __syncthreads();
    if (tid == 0) {
        __hip_atomic_fetch_add(ctr, 1u, __ATOMIC_ACQ_REL, __HIP_MEMORY_SCOPE_AGENT);
        while (__hip_atomic_load(ctr, __ATOMIC_ACQUIRE, __HIP_MEMORY_SCOPE_AGENT) < NBLK)
            __builtin_amdgcn_s_sleep(8);
    }
    __syncthreads();

    // ---- Fused tiles -----------------------------------------------------
    ushort_t* halo   = (ushort_t*)s_mem;                     // [0, 7776)
    float*    s_part = (float*)(s_mem + 7776);               // [7776, 11872)
    ushort_t* s_s    = (ushort_t*)s_mem;
    int n = lane & 15, quad = lane >> 4;

    for (int itile = 0; itile < TPB; ++itile) {
        int blk = bid*TPB + itile;            // 0..6399
        int jt = blk % 10, i = (blk/10) % Hq, b = blk/(10*Hq);
        int j0 = jt*16;
        const ushort_t* xtb = xt + (size_t)b*HWq*64;
        __syncthreads();                      // s_mem reuse guard

        // halo: 3 rows x 18 px x 64 ch bf16
        for (int t = tid; t < 432; t += 256) {
            int seg = t >> 3, sub = t & 7;
            int ky = seg / 18, px = seg % 18;
            int y = i + ky - 1, xx = j0 + px - 1;
            uint4 v = {0u,0u,0u,0u};
            if (y >= 0 && y < Hq && xx >= 0 && xx < Wq)
                v = *(const uint4*)(xtb + ((size_t)y*Wq + xx)*64 + sub*8);
            *(uint4*)(halo + (ky*18 + px)*HSTRIDE + sub*8) = v;
        }
        __syncthreads();

        // offset/mask conv: wave (gM, kh), 9 K-steps each
        {
            int gM = grp & 1, kh = grp >> 1;
            float4v cacc = {0.f,0.f,0.f,0.f};
#pragma unroll
            for (int s = 0; s < 9; ++s) {
                int st = kh*9 + s;
                int k = st >> 1, ks2 = st & 1;
                int ky = k/3, kx = k - (k/3)*3;
                short8 a  = *(const short8*)(cwf2 + (size_t)(((k*2+gM)*2+ks2)*512 + lane*8));
                short8 bf = *(const short8*)(halo + (ky*18 + n + kx)*HSTRIDE + quad*8 + ks2*32);
                cacc = __builtin_amdgcn_mfma_f32_16x16x32_bf16(a, bf, cacc, 0, 0, 0);
            }
            *(float4v*)(s_part + grp*256 + lane*4) = cacc;
        }
        __syncthreads();

        // Phase A: tap descriptors from conv partials
        if (tid < 144) {
            int p = tid & 15, k = tid >> 4;
            #define RD(co) (s_part[(((co)>>4)*256)     + ((((co)&15)>>2)*16 + p)*4 + ((co)&3)] + \
                            s_part[(2 + ((co)>>4))*256 + ((((co)&15)>>2)*16 + p)*4 + ((co)&3)])
            float oy = RD(2*k)   + off_b[2*k];
            float ox = RD(2*k+1) + off_b[2*k+1];
            float mv = RD(18+k)  + msk_b[k];
            #undef RD
            float m = 1.f/(1.f + __expf(-mv));
            float py = oy + (float)(i - 1 + k/3);
            float px = ox + (float)(j0 + p - 1 + (k - (k/3)*3));
            float fy = floorf(py), fx = floorf(px);
            int y0 = (int)fy, x0 = (int)fx;
            float wy1 = py - fy, wx1 = px - fx;
            float wy0 = 1.f - wy1, wx0 = 1.f - wx1;
            bool vy0 = (y0 >= 0) & (y0 < Hq),   vy1 = (y0+1 >= 0) & (y0+1 < Hq);
            bool vx0 = (x0 >= 0) & (x0 < Wq),   vx1 = (x0+1 >= 0) & (x0+1 < Wq);
            int yc0 = min(max(y0,   0), Hq-1), yc1 = min(max(y0+1, 0), Hq-1);
            int xc0 = min(max(x0,   0), Wq-1), xc1 = min(max(x0+1, 0), Wq-1);
            unsigned int* pk = s_pk + tid*12;
            pk[0] = (unsigned int)((yc0*Wq + xc0)*128);
            pk[1] = (unsigned int)((yc0*Wq + xc1)*128);
            pk[2] = (unsigned int)((yc1*Wq + xc0)*128);
            pk[3] = (unsigned int)((yc1*Wq + xc1)*128);
            pk[4] = __builtin_bit_cast(unsigned int, (vy0 && vx0) ? wy0*wx0*m : 0.f);
            pk[5] = __builtin_bit_cast(unsigned int, (vy0 && vx1) ? wy0*wx1*m : 0.f);
            pk[6] = __builtin_bit_cast(unsigned int, (vy1 && vx0) ? wy1*wx0*m : 0.f);
            pk[7] = __builtin_bit_cast(unsigned int, (vy1 && vx1) ? wy1*wx1*m : 0.f);
            pk[8] = (unsigned int)(p*(SROW*2) + k*128);
        }
        __syncthreads();

        // Phase B: half-wave per (p,tap), 2 channels/lane
        {
            int lane4 = (lane & 31) * 4;
            int halfi = lane >> 5;
            const char* xtbB = (const char*)xtb;
            char* s_sb = (char*)s_s;
#pragma unroll 2
            for (int iter = 0; iter < 18; ++iter) {
                int t2h = iter*8 + grp*2 + halfi;
                const uint4* pkp = (const uint4*)(s_pk + t2h*12);
                uint4 A  = pkp[0];
                uint4 Wt = pkp[1];
                unsigned int dst = s_pk[t2h*12 + 8];
                unsigned int u00 = *(const unsigned int*)(xtbB + A.x + lane4);
                unsigned int u01 = *(const unsigned int*)(xtbB + A.y + lane4);
                unsigned int u10 = *(const unsigned int*)(xtbB + A.z + lane4);
                unsigned int u11 = *(const unsigned int*)(xtbB + A.w + lane4);
                float w00 = __builtin_bit_cast(float, Wt.x);
                float w01 = __builtin_bit_cast(float, Wt.y);
                float w10 = __builtin_bit_cast(float, Wt.z);
                float w11 = __builtin_bit_cast(float, Wt.w);
                float sl = w00*bflo(u00) + w01*bflo(u01) + w10*bflo(u10) + w11*bflo(u11);
                float sh = w00*bfhi(u00) + w01*bfhi(u01) + w10*bfhi(u10) + w11*bfhi(u11);
                __hip_bfloat162 h2 = __float22bfloat162_rn(make_float2(sl, sh));
                *(__hip_bfloat162*)(s_sb + dst + lane4) = h2;
            }
        }
        __syncthreads();

        // Phase C: wave grp -> o rows [grp*16, +16), 16 pixels
        float4v acc = {0.f,0.f,0.f,0.f};
        const ushort_t* arow = wtf + ((size_t)(grp*KS)*64 + lane)*8;
        const ushort_t* brow = s_s + n*SROW + quad*8;
#pragma unroll
        for (int ks = 0; ks < KS; ++ks) {
            short8 a  = *(const short8*)(arow + ks*512);
            short8 bf = *(const short8*)(brow + ks*32);
            acc = __builtin_amdgcn_mfma_f32_16x16x32_bf16(a, bf, acc, 0, 0, 0);
        }
#pragma unroll
        for (int r = 0; r < 4; ++r) {
            int o = grp*16 + quad*4 + r;
            out[(((size_t)b*OUTq + o)*Hq + i)*Wq + j0 + n] = acc[r];
        }
    }
}

// ---------------------------------------------------------------------------
extern "C" void kernel_launch(void* const* d_in, const int* in_sizes, int n_in,
                              void* d_out, int out_size, void* d_ws, size_t ws_size,
                              hipStream_t stream) {
    const float* x     = (const float*)d_in[0];
    const float* off_w = (const float*)d_in[1];
    const float* off_b = (const float*)d_in[2];
    const float* msk_w = (const float*)d_in[3];
    const float* msk_b = (const float*)d_in[4];
    const float* dcn_w = (const float*)d_in[5];
    float* out = (float*)d_out;

    char* ws = (char*)d_ws;
    ushort_t* xt   = (ushort_t*)ws;                  // 13,107,200 B
    ushort_t* wtf  = xt + (size_t)Bq*HWq*64;         //     73,728 B
    ushort_t* cwf2 = wtf + 4*KS*512;                 //     36,864 B
    unsigned int* ctr = (unsigned int*)(cwf2 + 9*2*2*512);

    hipMemsetAsync(ctr, 0, 16, stream);
    hipLaunchKernelGGL(k_all, dim3(NBLK), dim3(256), 0, stream,
                       x, dcn_w, off_w, msk_w, off_b, msk_b,
                       xt, wtf, cwf2, ctr, out);
}

// Round 7
// 135.526 us; speedup vs baseline: 2.6366x; 2.6366x over previous
//
#include <hip/hip_runtime.h>
#include <hip/hip_bf16.h>
#include <math.h>

#define Bq 4
#define Cq 64
#define Hq 160
#define Wq 160
#define HWq (Hq*Wq)      // 25600
#define OUTq 64
#define KKq 576          // Cq*9
#define KS  18           // KKq/32
#define SROW 584         // padded kk row (bf16 units); 1168 B, rows 16B-aligned
#define HSTRIDE 72       // halo px stride (ushorts) = 144 B

typedef __attribute__((ext_vector_type(8))) short short8;
typedef __attribute__((ext_vector_type(4))) float float4v;
typedef __attribute__((ext_vector_type(2))) float float2v;
typedef unsigned short ushort_t;

__device__ __forceinline__ unsigned int f2bfu(float f) {   // RNE, as uint
    unsigned int u = __builtin_bit_cast(unsigned int, f);
    unsigned int r = u + 0x7fffu + ((u >> 16) & 1u);
    return r >> 16;
}
__device__ __forceinline__ float bflo(unsigned int u) {
    return __builtin_bit_cast(float, u << 16);
}
__device__ __forceinline__ float bfhi(unsigned int u) {
    return __builtin_bit_cast(float, u & 0xffff0000u);
}

// ---------------------------------------------------------------------------
// K_prep: x NCHW f32 -> xt NHWC bf16 (uint-vectorized stores), plus weight
// prepack piggybacked on the first 216 blocks of the y==0 slice.
//  wtf: A-frags of dcn_w, k-major kk = k*64+c.
//  cwf2: per-tap conv A-frags (27 rows offset+mask).
// ---------------------------------------------------------------------------
__global__ void __launch_bounds__(256) k_prep(const float* __restrict__ x,
                                              const float* __restrict__ dcn_w,
                                              const float* __restrict__ off_w,
                                              const float* __restrict__ msk_w,
                                              ushort_t* __restrict__ xt,
                                              ushort_t* __restrict__ wtf,
                                              ushort_t* __restrict__ cwf2) {
    __shared__ float tile[64][65];
    int b = blockIdx.y, hw0 = blockIdx.x * 64;
    int tid = threadIdx.x;
    int lane = tid & 63, grp = tid >> 6;
#pragma unroll
    for (int i = 0; i < 16; ++i) {
        int c = grp*16 + i;
        tile[c][lane] = x[(b*Cq + c)*HWq + hw0 + lane];
    }
    __syncthreads();
    int cp = tid & 31, hwg = tid >> 5;
#pragma unroll
    for (int it = 0; it < 8; ++it) {
        int hw = it*8 + hwg;
        unsigned int v = f2bfu(tile[2*cp][hw]) | (f2bfu(tile[2*cp+1][hw]) << 16);
        *(unsigned int*)(xt + ((size_t)b*HWq + hw0 + hw)*64 + 2*cp) = v;
    }
    if (blockIdx.y == 0 && blockIdx.x < 216) {
        int id = blockIdx.x*256 + tid;
        if (id < 4*KS*512) {
            int j = id & 7, ln = (id>>3) & 63, ks = (id>>9) % KS, g = id/(512*KS);
            int kk = ks*32 + (ln>>4)*8 + j;
            int c  = kk & 63, kt = kk >> 6;
            int m  = g*16 + (ln&15);
            wtf[id] = (ushort_t)f2bfu(dcn_w[m*KKq + c*9 + kt]);
        }
        int id2 = id - 4*KS*512;
        if (id2 >= 0 && id2 < 9*2*2*512) {
            int j = id2 & 7, ln = (id2>>3) & 63;
            int ks2 = (id2>>9) & 1, g = (id2>>10) & 1, k = id2 >> 11;
            int co = g*16 + (ln&15);
            int c  = ks2*32 + (ln>>4)*8 + j;
            float w = 0.f;
            if (co < 18)      w = off_w[co*KKq + c*9 + k];
            else if (co < 27) w = msk_w[(co-18)*KKq + c*9 + k];
            cwf2[id2] = (ushort_t)f2bfu(w);
        }
    }
}

// ---------------------------------------------------------------------------
// K_fused: per 16-px block: halo stage -> offset/mask conv (K-split MFMA) ->
// tap descriptors -> bilinear sampling -> main MFMA matmul -> store.
// LDS: union{halo(7776)+partials(4096) | s_s(18688)} + s_A(2304) + s_W(2304)
//    = 23,296 B -> 7 blocks/CU.
// ---------------------------------------------------------------------------
__global__ void __launch_bounds__(256, 7) k_fused(const ushort_t* __restrict__ xt,
                                                  const ushort_t* __restrict__ cwf2,
                                                  const float* __restrict__ off_b,
                                                  const float* __restrict__ msk_b,
                                                  const ushort_t* __restrict__ wtf,
                                                  float* __restrict__ out) {
    __shared__ __align__(16) char s_mem[16*SROW*2];          // 18,688 B
    __shared__ __align__(16) uint4  s_A[144];                //  2,304 B
    __shared__ __align__(16) float4 s_W[144];                //  2,304 B
    ushort_t* halo   = (ushort_t*)s_mem;                     // [0, 7776)
    float*    s_part = (float*)(s_mem + 7776);               // [7776, 11872)
    ushort_t* s_s    = (ushort_t*)s_mem;                     // Phase B/C

    int blk = blockIdx.x;                 // 6400 = 4 * 160 * 10
    int jt = blk % 10, i = (blk/10) % Hq, b = blk/(10*Hq);
    int j0 = jt*16;
    int tid = threadIdx.x, lane = tid & 63, grp = tid >> 6;
    int n = lane & 15, quad = lane >> 4;

    // ---- Stage halo: 3 rows x 18 px x 64 ch bf16 (54 x 128B segments) ----
    const ushort_t* xtb = xt + (size_t)b*HWq*64;
    for (int t = tid; t < 432; t += 256) {
        int seg = t >> 3, sub = t & 7;
        int ky = seg / 18, px = seg % 18;
        int y = i + ky - 1, xx = j0 + px - 1;
        uint4 v = {0u,0u,0u,0u};
        if (y >= 0 && y < Hq && xx >= 0 && xx < Wq)
            v = *(const uint4*)(xtb + ((size_t)y*Wq + xx)*64 + sub*8);
        *(uint4*)(halo + (ky*18 + px)*HSTRIDE + sub*8) = v;
    }
    __syncthreads();

    // ---- Offset/mask conv: wave (gM, kh) over 9 K-steps each ----
    {
        int gM = grp & 1, kh = grp >> 1;
        float4v cacc = {0.f,0.f,0.f,0.f};
#pragma unroll
        for (int s = 0; s < 9; ++s) {
            int st = kh*9 + s;            // 0..17
            int k = st >> 1, ks2 = st & 1;
            int ky = k/3, kx = k - (k/3)*3;
            short8 a  = *(const short8*)(cwf2 + (size_t)(((k*2+gM)*2+ks2)*512 + lane*8));
            short8 bf = *(const short8*)(halo + (ky*18 + n + kx)*HSTRIDE + quad*8 + ks2*32);
            cacc = __builtin_amdgcn_mfma_f32_16x16x32_bf16(a, bf, cacc, 0, 0, 0);
        }
        *(float4v*)(s_part + grp*256 + lane*4) = cacc;
    }
    __syncthreads();

    // ---- Phase A: tap descriptors from conv partials ----
    if (tid < 144) {
        int p = tid & 15, k = tid >> 4;
        #define RD(co) (s_part[(((co)>>4)*256)     + ((((co)&15)>>2)*16 + p)*4 + ((co)&3)] + \
                        s_part[(2 + ((co)>>4))*256 + ((((co)&15)>>2)*16 + p)*4 + ((co)&3)])
        float oy = RD(2*k)   + off_b[2*k];
        float ox = RD(2*k+1) + off_b[2*k+1];
        float mv = RD(18+k)  + msk_b[k];
        #undef RD
        float m = 1.f/(1.f + __expf(-mv));
        float py = oy + (float)(i - 1 + k/3);
        float px = ox + (float)(j0 + p - 1 + (k - (k/3)*3));
        float fy = floorf(py), fx = floorf(px);
        int y0 = (int)fy, x0 = (int)fx;
        float wy1 = py - fy, wx1 = px - fx;
        float wy0 = 1.f - wy1, wx0 = 1.f - wx1;
        bool vy0 = (y0 >= 0) & (y0 < Hq),   vy1 = (y0+1 >= 0) & (y0+1 < Hq);
        bool vx0 = (x0 >= 0) & (x0 < Wq),   vx1 = (x0+1 >= 0) & (x0+1 < Wq);
        int yc0 = min(max(y0,   0), Hq-1), yc1 = min(max(y0+1, 0), Hq-1);
        int xc0 = min(max(x0,   0), Wq-1), xc1 = min(max(x0+1, 0), Wq-1);
        s_A[tid] = make_uint4((unsigned int)((yc0*Wq + xc0)*128),
                              (unsigned int)((yc0*Wq + xc1)*128),
                              (unsigned int)((yc1*Wq + xc0)*128),
                              (unsigned int)((yc1*Wq + xc1)*128));
        s_W[tid] = make_float4((vy0 && vx0) ? wy0*wx0*m : 0.f,
                               (vy0 && vx1) ? wy0*wx1*m : 0.f,
                               (vy1 && vx0) ? wy1*wx0*m : 0.f,
                               (vy1 && vx1) ? wy1*wx1*m : 0.f);
    }
    __syncthreads();

    // ---- Phase B: half-wave per (p,tap), 2 ch/lane, packed f32 math ----
    {
        int lane4 = (lane & 31) * 4;
        int halfi = lane >> 5;
        const char* xtbB = (const char*)xtb;
        char* s_sb = (char*)s_s;
#pragma unroll 2
        for (int iter = 0; iter < 18; ++iter) {
            int t2h = iter*8 + grp*2 + halfi;
            uint4  A  = s_A[t2h];
            float4 Wt = s_W[t2h];
            unsigned int dst = (unsigned int)((t2h & 15)*(SROW*2) + (t2h >> 4)*128);
            unsigned int u00 = *(const unsigned int*)(xtbB + A.x + lane4);
            unsigned int u01 = *(const unsigned int*)(xtbB + A.y + lane4);
            unsigned int u10 = *(const unsigned int*)(xtbB + A.z + lane4);
            unsigned int u11 = *(const unsigned int*)(xtbB + A.w + lane4);
            float2v v00 = {bflo(u00), bfhi(u00)};
            float2v v01 = {bflo(u01), bfhi(u01)};
            float2v v10 = {bflo(u10), bfhi(u10)};
            float2v v11 = {bflo(u11), bfhi(u11)};
            float2v s2 = v00 * Wt.x;
            s2 += v01 * Wt.y;
            s2 += v10 * Wt.z;
            s2 += v11 * Wt.w;
            __hip_bfloat162 h2 = __float22bfloat162_rn(make_float2(s2.x, s2.y));
            *(__hip_bfloat162*)(s_sb + dst + lane4) = h2;
        }
    }
    __syncthreads();

    // ---- Phase C: wave grp -> o rows [grp*16, +16), 16 pixels ----
    float4v acc = {0.f,0.f,0.f,0.f};
    const ushort_t* arow = wtf + ((size_t)(grp*KS)*64 + lane)*8;
    const ushort_t* brow = s_s + n*SROW + quad*8;
#pragma unroll
    for (int ks = 0; ks < KS; ++ks) {
        short8 a  = *(const short8*)(arow + ks*512);
        short8 bf = *(const short8*)(brow + ks*32);
        acc = __builtin_amdgcn_mfma_f32_16x16x32_bf16(a, bf, acc, 0, 0, 0);
    }

#pragma unroll
    for (int r = 0; r < 4; ++r) {
        int o = grp*16 + quad*4 + r;
        out[(((size_t)b*OUTq + o)*Hq + i)*Wq + j0 + n] = acc[r];
    }
}

// ---------------------------------------------------------------------------
extern "C" void kernel_launch(void* const* d_in, const int* in_sizes, int n_in,
                              void* d_out, int out_size, void* d_ws, size_t ws_size,
                              hipStream_t stream) {
    const float* x     = (const float*)d_in[0];
    const float* off_w = (const float*)d_in[1];
    const float* off_b = (const float*)d_in[2];
    const float* msk_w = (const float*)d_in[3];
    const float* msk_b = (const float*)d_in[4];
    const float* dcn_w = (const float*)d_in[5];
    float* out = (float*)d_out;

    char* ws = (char*)d_ws;
    ushort_t* xt   = (ushort_t*)ws;                  // 13,107,200 B
    ushort_t* wtf  = xt + (size_t)Bq*HWq*64;         //     73,728 B
    ushort_t* cwf2 = wtf + 4*KS*512;                 //     36,864 B

    hipLaunchKernelGGL(k_prep, dim3(HWq/64, Bq), dim3(256), 0, stream,
                       x, dcn_w, off_w, msk_w, xt, wtf, cwf2);
    hipLaunchKernelGGL(k_fused, dim3(Bq*Hq*10), dim3(256), 0, stream,
                       xt, cwf2, off_b, msk_b, wtf, out);
}